// Round 15
// baseline (631.159 us; speedup 1.0000x reference)
//
#include <hip/hip_runtime.h>
#include <stdint.h>

// ---------------- problem constants ----------------
#define NE      16384
#define BATCH   4096
#define DFULL   1024
#define DHALF   512
#define TOPK    10
#define NCHUNK  16
#define CHUNK   1024            // entries per chunk (16384 / 16)
#define CPC     40              // candidates per row per chunk (2 wr * 4 q * 5)
#define NCAND   (NCHUNK * CPC)  // 640 candidates per row
#define MRES    24              // exact-rescore count
#define BETA_C  0.25f
#define CD1     ((size_t)BATCH * NCAND)

// output layout offsets (floats)
#define O1 ((size_t)BATCH * DFULL)
#define O2 (O1 + (size_t)BATCH * DHALF)
#define O3 (O2 + (size_t)BATCH * DHALF)
#define O4 (O3 + (size_t)BATCH * DHALF)
#define O5 (O4 + (size_t)BATCH * DHALF)

typedef __bf16 bf16x8 __attribute__((ext_vector_type(8)));
typedef float  f32x4  __attribute__((ext_vector_type(4)));

__device__ inline uint16_t f2bf(float f) {
    unsigned u = __float_as_uint(f);
    unsigned r = (u + 0x7FFFu + ((u >> 16) & 1u)) >> 16;
    return (uint16_t)r;
}
__device__ inline float bf2f(uint16_t u) {
    return __uint_as_float(((unsigned)u) << 16);
}
// dot of 8 packed bf16 (uint4) with 8 f32
__device__ inline float dot8bf(uint4 e, const float* zp) {
    float s;
    s  = __uint_as_float(e.x << 16)          * zp[0];
    s += __uint_as_float(e.x & 0xFFFF0000u)  * zp[1];
    s += __uint_as_float(e.y << 16)          * zp[2];
    s += __uint_as_float(e.y & 0xFFFF0000u)  * zp[3];
    s += __uint_as_float(e.z << 16)          * zp[4];
    s += __uint_as_float(e.z & 0xFFFF0000u)  * zp[5];
    s += __uint_as_float(e.w << 16)          * zp[6];
    s += __uint_as_float(e.w & 0xFFFF0000u)  * zp[7];
    return s;
}

// ---------------- normalization kernels ----------------
__global__ __launch_bounds__(256) void k_norm_z(const float* __restrict__ z,
                                                uint16_t* __restrict__ zn,
                                                float* __restrict__ rnzt,
                                                float* __restrict__ rnzg) {
    int b = blockIdx.x, t = threadIdx.x;
    const float4* zp = (const float4*)(z + (size_t)b * DFULL);
    float4 v = zp[t];
    float ss = v.x*v.x + v.y*v.y + v.z*v.z + v.w*v.w;
    #pragma unroll
    for (int off = 32; off; off >>= 1) ss += __shfl_xor(ss, off);
    __shared__ float red[4];
    if ((t & 63) == 0) red[t >> 6] = ss;
    __syncthreads();
    float tot = (t < 128) ? (red[0] + red[1]) : (red[2] + red[3]);
    float rn = rsqrtf(tot + 1e-12f);
    if (t == 0)   rnzt[b] = rn;
    if (t == 128) rnzg[b] = rn;
    uint16_t* o = zn + (size_t)b * DFULL + t * 4;
    o[0] = f2bf(v.x * rn); o[1] = f2bf(v.y * rn);
    o[2] = f2bf(v.z * rn); o[3] = f2bf(v.w * rn);
}

// fused: all 4 codebook normalizations in one dispatch, grid (NE, 4)
__global__ __launch_bounds__(128) void k_norm_cb_all(
    const float* __restrict__ w_st, const float* __restrict__ w_sg,
    const float* __restrict__ w_t,  const float* __restrict__ w_g,
    uint16_t* __restrict__ wsh, uint16_t* __restrict__ wt, uint16_t* __restrict__ wg,
    float* __restrict__ rns /* [4*NE]: st, sg, t, g */) {
    int r = blockIdx.x, t = threadIdx.x, y = blockIdx.y;
    const float* w; uint16_t* dst; int dstld; float* rn_;
    if (y == 0)      { w = w_st; dst = wsh;       dstld = DFULL; rn_ = rns; }
    else if (y == 1) { w = w_sg; dst = wsh + 512; dstld = DFULL; rn_ = rns + NE; }
    else if (y == 2) { w = w_t;  dst = wt;        dstld = DHALF; rn_ = rns + 2 * NE; }
    else             { w = w_g;  dst = wg;        dstld = DHALF; rn_ = rns + 3 * NE; }
    const float4* wp = (const float4*)(w + (size_t)r * DHALF);
    float4 v = wp[t];
    float ss = v.x*v.x + v.y*v.y + v.z*v.z + v.w*v.w;
    #pragma unroll
    for (int off = 32; off; off >>= 1) ss += __shfl_xor(ss, off);
    __shared__ float red[2];
    if ((t & 63) == 0) red[t >> 6] = ss;
    __syncthreads();
    float rn = rsqrtf(red[0] + red[1] + 1e-12f);
    if (t == 0) rn_[r] = rn;
    uint16_t* o = dst + (size_t)r * dstld + t * 4;
    o[0] = f2bf(v.x * rn); o[1] = f2bf(v.y * rn);
    o[2] = f2bf(v.z * rn); o[3] = f2bf(v.w * rn);
}

// ---------------- fused GEMM (S^T) + per-lane register top-5 screen ----------
// R14 cycle audit: LDS pipe is the wall (130KB/block-kt at 85 B/cy = 86% of
// the 380us). This round: WAVE TILE 64x64 (acc[4][4]) — 16 ds_read_b128 per
// lane-kt feed 32 MFMA (0.5 reads/MFMA vs 0.75) -> per-CU LDS bytes/MFMA
// -33%. Block = 128 ents x 256 batch, 8 waves (2 wr x 4 wc), 96KB LDS ->
// 1 block/CU, 2 waves/SIMD. TLP loss is acceptable: the binding resource is
// the per-CU LDS pipe; staging loads are issued ~2000cy before their drain.
// Screen bucket structure (wr x q per batch row) unchanged -> scores and
// output byte-identical to R13/R14 (absmax 1.53e-2).
__global__ __launch_bounds__(512, 2) void k_gemm_topk(
    const uint16_t* __restrict__ Zn,
    const uint16_t* __restrict__ wshn, const uint16_t* __restrict__ wtn,
    const uint16_t* __restrict__ wgn,
    unsigned* __restrict__ cand)
{
    __shared__ uint16_t Wsm[2][128 * 64];   // entries x k, XOR-swizzled 128B rows (32KB)
    __shared__ uint16_t Zsm[2][256 * 64];   // batch   x k (64KB)

    const int tid  = threadIdx.x;
    const int lane = tid & 63;
    const int wv   = tid >> 6;      // 0..7
    const int wr   = wv >> 2;       // entry half (0..1)
    const int wc   = wv & 3;        // batch quarter (0..3), 64 rows each
    const int q    = lane >> 4;     // k-group / entry row group
    const int c    = lane & 15;
    const int rowbase  = blockIdx.y * 256;     // batch rows
    const int entchunk = blockIdx.x * CHUNK;   // entry base
    const int gz = blockIdx.z;

    const uint16_t* Wn; int ldw, KT, zoff; unsigned* cdst;
    if (gz == 0)      { Wn = wshn; ldw = DFULL; KT = 16; zoff = 0;   cdst = cand; }
    else if (gz == 1) { Wn = wtn;  ldw = DHALF; KT = 8;  zoff = 0;   cdst = cand + CD1; }
    else              { Wn = wgn;  ldw = DHALF; KT = 8;  zoff = 512; cdst = cand + 2 * CD1; }
    const int ldz = DFULL;

    // ---- hoisted per-thread staging offsets (bytes) ----
    // slot i covers LDS bytes [(i*8+wv)*1024 + lane*16 .. +16)
    // W: i in {0,1} (16KB); Z: i in {0..3} (32KB)
    int sw_o0, sw_o1, lw_o0, lw_o1;
    int sz_o0, sz_o1, sz_o2, sz_o3, lz_o0, lz_o1, lz_o2, lz_o3;
    {
        int o, row, kb;
        o = (0 * 8 + wv) * 1024 + lane * 16; row = o >> 7; kb = (o & 127) ^ ((row & 7) << 4);
        sw_o0 = row * (ldw * 2) + kb; lw_o0 = o;
        sz_o0 = row * (ldz * 2) + kb; lz_o0 = o;
        o = (1 * 8 + wv) * 1024 + lane * 16; row = o >> 7; kb = (o & 127) ^ ((row & 7) << 4);
        sw_o1 = row * (ldw * 2) + kb; lw_o1 = o;
        sz_o1 = row * (ldz * 2) + kb; lz_o1 = o;
        o = (2 * 8 + wv) * 1024 + lane * 16; row = o >> 7; kb = (o & 127) ^ ((row & 7) << 4);
        sz_o2 = row * (ldz * 2) + kb; lz_o2 = o;
        o = (3 * 8 + wv) * 1024 + lane * 16; row = o >> 7; kb = (o & 127) ^ ((row & 7) << 4);
        sz_o3 = row * (ldz * 2) + kb; lz_o3 = o;
    }

    const char* Wbase = (const char*)Wn;
    const char* Zbase = (const char*)(Zn + zoff);

    // per-lane sorted top-5 lists, 4 batch rows (n=0..3), all NAMED registers
    unsigned La0 = 0, La1 = 0, La2 = 0, La3 = 0, La4 = 0;
    unsigned Lb0 = 0, Lb1 = 0, Lb2 = 0, Lb3 = 0, Lb4 = 0;
    unsigned Lc0 = 0, Lc1 = 0, Lc2 = 0, Lc3 = 0, Lc4 = 0;
    unsigned Ld0 = 0, Ld1 = 0, Ld2 = 0, Ld3 = 0, Ld4 = 0;

    // named staging registers (6 x uint4 = 24 VGPR, never in memory)
    uint4 sw0, sw1, sz0, sz1, sz2, sz3;

#define LOADG(cb2, kt2) {                                                           \
        const char* Wg = Wbase + ((size_t)(entchunk + (cb2) * 128) * ldw + (kt2) * 64) * 2; \
        const char* Zg = Zbase + ((size_t)rowbase * ldz + (kt2) * 64) * 2;          \
        sw0 = *(const uint4*)(Wg + sw_o0);                                          \
        sw1 = *(const uint4*)(Wg + sw_o1);                                          \
        sz0 = *(const uint4*)(Zg + sz_o0);                                          \
        sz1 = *(const uint4*)(Zg + sz_o1);                                          \
        sz2 = *(const uint4*)(Zg + sz_o2);                                          \
        sz3 = *(const uint4*)(Zg + sz_o3);                                          \
    }
#define WRITES(bufi) {                                                              \
        char* Wd = (char*)&Wsm[bufi][0];                                            \
        char* Zd = (char*)&Zsm[bufi][0];                                            \
        *(uint4*)(Wd + lw_o0) = sw0;                                                \
        *(uint4*)(Wd + lw_o1) = sw1;                                                \
        *(uint4*)(Zd + lz_o0) = sz0;                                                \
        *(uint4*)(Zd + lz_o1) = sz1;                                                \
        *(uint4*)(Zd + lz_o2) = sz2;                                                \
        *(uint4*)(Zd + lz_o3) = sz3;                                                \
    }
// branchless sorted top-5 insert into 5 named regs
#define INS5(p, X0, X1, X2, X3, X4) {                                               \
        bool g0 = (p) > X0, g1 = (p) > X1, g2 = (p) > X2,                           \
             g3 = (p) > X3, g4 = (p) > X4;                                          \
        X4 = g4 ? (g3 ? X3 : (p)) : X4;                                             \
        X3 = g3 ? (g2 ? X2 : (p)) : X3;                                             \
        X2 = g2 ? (g1 ? X1 : (p)) : X2;                                             \
        X1 = g1 ? (g0 ? X0 : (p)) : X1;                                             \
        X0 = g0 ? (p) : X0;                                                         \
    }

    LOADG(0, 0);
    WRITES(0);
    __syncthreads();
    int cur = 0;

    for (int cb = 0; cb < 8; ++cb) {
        f32x4 acc[4][4];
        #pragma unroll
        for (int m = 0; m < 4; ++m)
            #pragma unroll
            for (int n = 0; n < 4; ++n)
                acc[m][n] = (f32x4){0.f, 0.f, 0.f, 0.f};

        for (int kt = 0; kt < KT; ++kt) {
            int last = (kt + 1 == KT);
            int ncb = last ? cb + 1 : cb;
            int nkt = last ? 0 : kt + 1;
            int havenext = (ncb < 8);
            if (havenext) LOADG(ncb, nkt);   // issue loads; latency hides under compute

            const char* Wb = (const char*)&Wsm[cur][0];
            const char* Zb = (const char*)&Zsm[cur][0];
            #pragma unroll
            for (int ks = 0; ks < 2; ++ks) {
                int kb = ks * 64 + q * 16;
                bf16x8 b[4];
                #pragma unroll
                for (int n = 0; n < 4; ++n) {
                    int rb = wc * 64 + n * 16 + c;
                    b[n] = *(const bf16x8*)(Zb + rb * 128 + (kb ^ ((rb & 7) << 4)));
                }
                #pragma unroll
                for (int m = 0; m < 4; ++m) {
                    int ra = wr * 64 + m * 16 + c;
                    bf16x8 a = *(const bf16x8*)(Wb + ra * 128 + (kb ^ ((ra & 7) << 4)));
                    #pragma unroll
                    for (int n = 0; n < 4; ++n)
                        acc[m][n] = __builtin_amdgcn_mfma_f32_16x16x32_bf16(
                                        a, b[n], acc[m][n], 0, 0, 0);
                }
            }

            if (havenext) WRITES(cur ^ 1);   // vmcnt wait lands here, post-compute
            __syncthreads();                 // drains LDS writes only (cheap)
            cur ^= 1;
        }

        // ---- per-lane branchless top-5 screen (no cross-lane ops) ----
        const int entbase = entchunk + cb * 128 + wr * 64 + q * 4;
        #pragma unroll
        for (int n = 0; n < 4; ++n) {
            #pragma unroll
            for (int m = 0; m < 4; ++m) {
                #pragma unroll
                for (int i = 0; i < 4; ++i) {
                    unsigned u  = __float_as_uint(acc[m][n][i]);
                    unsigned mg = (unsigned)((int)u >> 31);
                    unsigned h  = (u >> 16) ^ (mg | 0x8000u);
                    unsigned p  = (h << 16) | (unsigned)(entbase + m * 16 + i);
                    if (n == 0)      { INS5(p, La0, La1, La2, La3, La4); }
                    else if (n == 1) { INS5(p, Lb0, Lb1, Lb2, Lb3, Lb4); }
                    else if (n == 2) { INS5(p, Lc0, Lc1, Lc2, Lc3, Lc4); }
                    else             { INS5(p, Ld0, Ld1, Ld2, Ld3, Ld4); }
                }
            }
        }
    }

    // write per-lane lists: cand[row][chunk][wr][q][5]
    {
        unsigned* dst;
        int grow;
        grow = rowbase + wc * 64 + 0 * 16 + c;
        dst = cdst + ((size_t)grow * NCHUNK + blockIdx.x) * CPC + wr * 20 + q * 5;
        dst[0] = La0; dst[1] = La1; dst[2] = La2; dst[3] = La3; dst[4] = La4;
        grow = rowbase + wc * 64 + 1 * 16 + c;
        dst = cdst + ((size_t)grow * NCHUNK + blockIdx.x) * CPC + wr * 20 + q * 5;
        dst[0] = Lb0; dst[1] = Lb1; dst[2] = Lb2; dst[3] = Lb3; dst[4] = Lb4;
        grow = rowbase + wc * 64 + 2 * 16 + c;
        dst = cdst + ((size_t)grow * NCHUNK + blockIdx.x) * CPC + wr * 20 + q * 5;
        dst[0] = Lc0; dst[1] = Lc1; dst[2] = Lc2; dst[3] = Lc3; dst[4] = Lc4;
        grow = rowbase + wc * 64 + 3 * 16 + c;
        dst = cdst + ((size_t)grow * NCHUNK + blockIdx.x) * CPC + wr * 20 + q * 5;
        dst[0] = Ld0; dst[1] = Ld1; dst[2] = Ld2; dst[3] = Ld3; dst[4] = Ld4;
    }
#undef LOADG
#undef WRITES
#undef INS5
}

// ---------------- fused merge: all 3 codebooks in one dispatch ----------------
// grid (BATCH, 3). Rescore + mix from bf16 NORMALIZED books (L3-resident),
// f32 z in LDS, f32 accum, scaled by rnz. UNCHANGED from R13 (absmax 1.53e-2,
// deterministic) — scoring path must stay byte-identical.
__global__ __launch_bounds__(256) void k_merge_all(
    const unsigned* __restrict__ cand,
    const uint16_t* __restrict__ wshn, const uint16_t* __restrict__ wtn,
    const uint16_t* __restrict__ wgn,
    const float* __restrict__ rnzt, const float* __restrict__ rnzg,
    const float* __restrict__ z, float* __restrict__ out,
    unsigned int* __restrict__ bm, float* __restrict__ ls)
{
    const int b = blockIdx.x, g = blockIdx.y, tid = threadIdx.x;
    const int lane = tid & 63, wv = tid >> 6;

    // per-codebook config (wave-uniform)
    const unsigned* cd; const uint16_t* emb;
    int zoff, ld;
    float *outm, *outs1, *outs2;
    float rz0, rz1;
    if (g == 0) {
        cd = cand;           emb = wshn; zoff = 0;   ld = DFULL;
        outm = out; outs1 = out + O1; outs2 = out + O2;
        rz0 = rnzt[b]; rz1 = rnzg[b];
    } else if (g == 1) {
        cd = cand + CD1;     emb = wtn;  zoff = 0;   ld = DHALF;
        outm = out + O3; outs1 = nullptr; outs2 = nullptr;
        rz0 = rnzt[b]; rz1 = 0.f;
    } else {
        cd = cand + 2 * CD1; emb = wgn;  zoff = 512; ld = DHALF;
        outm = out + O4; outs1 = nullptr; outs2 = nullptr;
        rz0 = rnzg[b]; rz1 = 0.f;
    }
    unsigned int* bitmap = bm + g * (NE / 32);
    float* lossacc = ls + g;

    __shared__ float zsh[DFULL];
    __shared__ unsigned scand[MRES];
    __shared__ float ssh[MRES];
    __shared__ float wts[TOPK];
    __shared__ int   ish[TOPK];
    __shared__ float serr[4];

    const float* zrow = z + (size_t)b * DFULL + zoff;
    for (int cc = tid; cc < ld / 4; cc += 256)
        ((float4*)zsh)[cc] = ((const float4*)zrow)[cc];

    // wave 0: top-24 of 640 packed candidates (value-clear extraction)
    if (wv == 0) {
        unsigned creg[10];
        const unsigned* cb_ = cd + (size_t)b * NCAND;
        #pragma unroll
        for (int j = 0; j < 10; ++j) creg[j] = cb_[lane + 64 * j];
        for (int k = 0; k < MRES; ++k) {
            unsigned bv = 0;
            #pragma unroll
            for (int j = 0; j < 10; ++j) bv = (creg[j] > bv) ? creg[j] : bv;
            #pragma unroll
            for (int off = 32; off; off >>= 1) {
                unsigned ov = __shfl_xor(bv, off);
                bv = (ov > bv) ? ov : bv;
            }
            #pragma unroll
            for (int j = 0; j < 10; ++j) if (creg[j] == bv) creg[j] = 0u;
            if (lane == 0) scand[k] = bv;
        }
    }
    __syncthreads();

    // rescore the 24 survivors: bf16 normalized books x f32 z, f32 accum
    for (int cc = wv; cc < MRES; cc += 4) {
        int idx = scand[cc] & 0xFFFFu;
        const uint16_t* er = emb + (size_t)idx * ld;
        uint4 e0 = *(const uint4*)(er + lane * 8);
        float t = rz0 * dot8bf(e0, zsh + lane * 8);
        if (ld == DFULL) {
            uint4 e1 = *(const uint4*)(er + 512 + lane * 8);
            t += rz1 * dot8bf(e1, zsh + 512 + lane * 8);
        }
        #pragma unroll
        for (int off = 32; off; off >>= 1) t += __shfl_xor(t, off);
        if (lane == 0) ssh[cc] = t;
    }
    __syncthreads();

    // wave 0: top-10 of 24 -> softmax weights
    if (wv == 0) {
        float val = (lane < MRES) ? ssh[lane] : -1e30f;
        float vk[TOPK]; int sk[TOPK];
        #pragma unroll
        for (int k = 0; k < TOPK; ++k) {
            float v = val; int who = lane;
            #pragma unroll
            for (int off = 32; off; off >>= 1) {
                float ov = __shfl_xor(v, off);
                int   ow = __shfl_xor(who, off);
                if (ov > v || (ov == v && ow < who)) { v = ov; who = ow; }
            }
            vk[k] = v; sk[k] = who;
            if (lane == who) val = -1e30f;
        }
        if (lane == 0) {
            float vmax = vk[0], e[TOPK], sum = 0.f;
            #pragma unroll
            for (int k = 0; k < TOPK; ++k) { e[k] = expf(2.f * (vk[k] - vmax)); sum += e[k]; }
            #pragma unroll
            for (int k = 0; k < TOPK; ++k) {
                float w = e[k] / sum;
                int idx = scand[sk[k]] & 0xFFFFu;
                ish[k] = idx;
                wts[k] = w;
                atomicOr(&bitmap[idx >> 5], 1u << (idx & 31));
            }
        }
    }
    __syncthreads();

    float wk[TOPK]; int ik[TOPK];
    #pragma unroll
    for (int k = 0; k < TOPK; ++k) { wk[k] = wts[k]; ik[k] = ish[k]; }

    // mix from bf16 NORMALIZED codebook rows (8B gathers), write outputs, loss
    float err = 0.f;
    const int ng = ld / 4;
    for (int g2 = tid; g2 < ng; g2 += 256) {
        float ax = 0.f, ay = 0.f, az = 0.f, aw = 0.f;
        #pragma unroll
        for (int k = 0; k < TOPK; ++k) {
            ushort4 e = ((const ushort4*)(emb + (size_t)ik[k] * ld))[g2];
            float wv_ = wk[k];
            ax += wv_ * bf2f(e.x); ay += wv_ * bf2f(e.y);
            az += wv_ * bf2f(e.z); aw += wv_ * bf2f(e.w);
        }
        float4 zz = ((const float4*)zsh)[g2];
        float dx = ax - zz.x, dy = ay - zz.y, dz_ = az - zz.z, dw = aw - zz.w;
        err += dx*dx + dy*dy + dz_*dz_ + dw*dw;
        float4 a4 = {ax, ay, az, aw};
        ((float4*)(outm + (size_t)b * ld))[g2] = a4;
        if (outs1) {
            if (g2 < 128) ((float4*)(outs1 + (size_t)b * DHALF))[g2] = a4;
            else          ((float4*)(outs2 + (size_t)b * DHALF))[g2 - 128] = a4;
        }
    }
    #pragma unroll
    for (int off = 32; off; off >>= 1) err += __shfl_xor(err, off);
    if (lane == 0) serr[wv] = err;
    __syncthreads();
    if (tid == 0) atomicAdd(lossacc, serr[0] + serr[1] + serr[2] + serr[3]);
}

// ---------------- scalar outputs ----------------
__global__ __launch_bounds__(256) void k_scalars(const unsigned int* __restrict__ bm,
                                                 const float* __restrict__ lossacc,
                                                 float* __restrict__ out)
{
    __shared__ float red[4];
    int tid = threadIdx.x;
    float counts[3];
    for (int g = 0; g < 3; ++g) {
        unsigned c = 0;
        for (int w = tid; w < NE / 32; w += 256) c += __popc(bm[g * (NE / 32) + w]);
        float f = (float)c;
        #pragma unroll
        for (int off = 32; off; off >>= 1) f += __shfl_xor(f, off);
        if ((tid & 63) == 0) red[tid >> 6] = f;
        __syncthreads();
        counts[g] = red[0] + red[1] + red[2] + red[3];
        __syncthreads();
    }
    if (tid == 0) {
        float vq_s = lossacc[0] / (4096.f * 1024.f);
        float vq_t = lossacc[1] / (4096.f * 512.f);
        float vq_g = lossacc[2] / (4096.f * 512.f);
        out[0] = vq_s; out[1] = BETA_C * vq_s;
        out[2] = vq_t; out[3] = BETA_C * vq_t;
        out[4] = vq_g; out[5] = BETA_C * vq_g;
        out[6] = counts[0] / (float)NE;
        out[7] = counts[1] / (float)NE;
        out[8] = counts[2] / (float)NE;
    }
}

// ---------------- host launch ----------------
extern "C" void kernel_launch(void* const* d_in, const int* in_sizes, int n_in,
                              void* d_out, int out_size, void* d_ws, size_t ws_size,
                              hipStream_t stream) {
    const float* z    = (const float*)d_in[0];
    const float* w_t  = (const float*)d_in[1];
    const float* w_g  = (const float*)d_in[2];
    const float* w_st = (const float*)d_in[3];
    const float* w_sg = (const float*)d_in[4];
    float* out = (float*)d_out;

    uint8_t* ws = (uint8_t*)d_ws;
    const size_t OFF_ZN  = 0;                                          // bf16 [4096,1024]
    const size_t OFF_WSH = OFF_ZN  + (size_t)BATCH * DFULL * 2;        // bf16 [16384,1024]
    const size_t OFF_WT  = OFF_WSH + (size_t)NE * DFULL * 2;           // bf16 [16384,512]
    const size_t OFF_WG  = OFF_WT  + (size_t)NE * DHALF * 2;
    const size_t OFF_CD  = OFF_WG  + (size_t)NE * DHALF * 2;           // 3*4096*640 u32
    const size_t OFF_RN  = OFF_CD  + (size_t)3 * BATCH * NCAND * 4;
    const size_t OFF_RNZ = OFF_RN  + (size_t)4 * NE * 4;
    const size_t OFF_BM  = OFF_RNZ + (size_t)2 * BATCH * 4;
    const size_t OFF_LS  = OFF_BM  + (size_t)3 * (NE / 8);

    uint16_t* zn   = (uint16_t*)(ws + OFF_ZN);
    uint16_t* wsh  = (uint16_t*)(ws + OFF_WSH);
    uint16_t* wt   = (uint16_t*)(ws + OFF_WT);
    uint16_t* wg   = (uint16_t*)(ws + OFF_WG);
    unsigned* cd   = (unsigned*)(ws + OFF_CD);
    float*    rns  = (float*)(ws + OFF_RN);
    float*    rnzt = (float*)(ws + OFF_RNZ);
    float*    rnzg = rnzt + BATCH;
    unsigned* bm   = (unsigned*)(ws + OFF_BM);
    float*    ls   = (float*)(ws + OFF_LS);

    hipMemsetAsync(ws + OFF_BM, 0, 3 * (NE / 8) + 64, stream);

    k_norm_z<<<BATCH, 256, 0, stream>>>(z, zn, rnzt, rnzg);
    k_norm_cb_all<<<dim3(NE, 4), 128, 0, stream>>>(w_st, w_sg, w_t, w_g,
                                                   wsh, wt, wg, rns);

    k_gemm_topk<<<dim3(NCHUNK, BATCH / 256, 3), 512, 0, stream>>>(zn, wsh, wt, wg, cd);

    k_merge_all<<<dim3(BATCH, 3), 256, 0, stream>>>(
        cd, wsh, wt, wg, rnzt, rnzg, z, out, bm, ls);

    k_scalars<<<1, 256, 0, stream>>>(bm, ls, out + O5);
}

// Round 16
// 614.158 us; speedup vs baseline: 1.0277x; 1.0277x over previous
//
#include <hip/hip_runtime.h>
#include <stdint.h>

// ---------------- problem constants ----------------
#define NE      16384
#define BATCH   4096
#define DFULL   1024
#define DHALF   512
#define TOPK    10
#define NCHUNK  16
#define CHUNK   1024            // entries per chunk (16384 / 16)
#define CPC     40              // candidates per row per chunk (2 wr * 4 q * 5)
#define NCAND   (NCHUNK * CPC)  // 640 candidates per row
#define MRES    24              // exact-rescore count
#define BETA_C  0.25f
#define CD1     ((size_t)BATCH * NCAND)

// output layout offsets (floats)
#define O1 ((size_t)BATCH * DFULL)
#define O2 (O1 + (size_t)BATCH * DHALF)
#define O3 (O2 + (size_t)BATCH * DHALF)
#define O4 (O3 + (size_t)BATCH * DHALF)
#define O5 (O4 + (size_t)BATCH * DHALF)

typedef __bf16 bf16x8 __attribute__((ext_vector_type(8)));
typedef float  f32x4  __attribute__((ext_vector_type(4)));

__device__ inline uint16_t f2bf(float f) {
    unsigned u = __float_as_uint(f);
    unsigned r = (u + 0x7FFFu + ((u >> 16) & 1u)) >> 16;
    return (uint16_t)r;
}
__device__ inline float bf2f(uint16_t u) {
    return __uint_as_float(((unsigned)u) << 16);
}
// dot of 8 packed bf16 (uint4) with 8 f32
__device__ inline float dot8bf(uint4 e, const float* zp) {
    float s;
    s  = __uint_as_float(e.x << 16)          * zp[0];
    s += __uint_as_float(e.x & 0xFFFF0000u)  * zp[1];
    s += __uint_as_float(e.y << 16)          * zp[2];
    s += __uint_as_float(e.y & 0xFFFF0000u)  * zp[3];
    s += __uint_as_float(e.z << 16)          * zp[4];
    s += __uint_as_float(e.z & 0xFFFF0000u)  * zp[5];
    s += __uint_as_float(e.w << 16)          * zp[6];
    s += __uint_as_float(e.w & 0xFFFF0000u)  * zp[7];
    return s;
}

// ---------------- normalization kernels ----------------
__global__ __launch_bounds__(256) void k_norm_z(const float* __restrict__ z,
                                                uint16_t* __restrict__ zn,
                                                float* __restrict__ rnzt,
                                                float* __restrict__ rnzg) {
    int b = blockIdx.x, t = threadIdx.x;
    const float4* zp = (const float4*)(z + (size_t)b * DFULL);
    float4 v = zp[t];
    float ss = v.x*v.x + v.y*v.y + v.z*v.z + v.w*v.w;
    #pragma unroll
    for (int off = 32; off; off >>= 1) ss += __shfl_xor(ss, off);
    __shared__ float red[4];
    if ((t & 63) == 0) red[t >> 6] = ss;
    __syncthreads();
    float tot = (t < 128) ? (red[0] + red[1]) : (red[2] + red[3]);
    float rn = rsqrtf(tot + 1e-12f);
    if (t == 0)   rnzt[b] = rn;
    if (t == 128) rnzg[b] = rn;
    uint16_t* o = zn + (size_t)b * DFULL + t * 4;
    o[0] = f2bf(v.x * rn); o[1] = f2bf(v.y * rn);
    o[2] = f2bf(v.z * rn); o[3] = f2bf(v.w * rn);
}

// fused: all 4 codebook normalizations in one dispatch, grid (NE, 4)
__global__ __launch_bounds__(128) void k_norm_cb_all(
    const float* __restrict__ w_st, const float* __restrict__ w_sg,
    const float* __restrict__ w_t,  const float* __restrict__ w_g,
    uint16_t* __restrict__ wsh, uint16_t* __restrict__ wt, uint16_t* __restrict__ wg,
    float* __restrict__ rns /* [4*NE]: st, sg, t, g */) {
    int r = blockIdx.x, t = threadIdx.x, y = blockIdx.y;
    const float* w; uint16_t* dst; int dstld; float* rn_;
    if (y == 0)      { w = w_st; dst = wsh;       dstld = DFULL; rn_ = rns; }
    else if (y == 1) { w = w_sg; dst = wsh + 512; dstld = DFULL; rn_ = rns + NE; }
    else if (y == 2) { w = w_t;  dst = wt;        dstld = DHALF; rn_ = rns + 2 * NE; }
    else             { w = w_g;  dst = wg;        dstld = DHALF; rn_ = rns + 3 * NE; }
    const float4* wp = (const float4*)(w + (size_t)r * DHALF);
    float4 v = wp[t];
    float ss = v.x*v.x + v.y*v.y + v.z*v.z + v.w*v.w;
    #pragma unroll
    for (int off = 32; off; off >>= 1) ss += __shfl_xor(ss, off);
    __shared__ float red[2];
    if ((t & 63) == 0) red[t >> 6] = ss;
    __syncthreads();
    float rn = rsqrtf(red[0] + red[1] + 1e-12f);
    if (t == 0) rn_[r] = rn;
    uint16_t* o = dst + (size_t)r * dstld + t * 4;
    o[0] = f2bf(v.x * rn); o[1] = f2bf(v.y * rn);
    o[2] = f2bf(v.z * rn); o[3] = f2bf(v.w * rn);
}

// ---------------- fused GEMM (S^T) + per-lane register top-5 screen ----------
// R14 CONFIG (best measured: gemm 380us, total 627us). 512 threads = 8 waves
// (2 ent-half x 4 batch-quarter), block tile 128 ents x 128 batch, wave tile
// 64x32, 64KB LDS -> 2 blocks/CU = 4 waves/SIMD.
// Structure probes R10/R11/R15 (Z-direct, Z-prefetch, 64x64 wave tile) all
// regressed: the LDS-bytes/MFMA lever is real but every pull loses more to
// coalescing or TLP. Per-lane reads/8-MFMA already minimal (4A+2B).
__global__ __launch_bounds__(512, 4) void k_gemm_topk(
    const uint16_t* __restrict__ Zn,
    const uint16_t* __restrict__ wshn, const uint16_t* __restrict__ wtn,
    const uint16_t* __restrict__ wgn,
    unsigned* __restrict__ cand)
{
    __shared__ uint16_t Wsm[2][128 * 64];   // entries x k, XOR-swizzled 128B rows (32KB)
    __shared__ uint16_t Zsm[2][128 * 64];   // batch   x k (32KB)

    const int tid  = threadIdx.x;
    const int lane = tid & 63;
    const int wv   = tid >> 6;      // 0..7
    const int wr   = wv >> 2;       // entry half (0..1)
    const int wc   = wv & 3;        // batch quarter (0..3)
    const int q    = lane >> 4;     // k-group / entry row group
    const int c    = lane & 15;
    const int rowbase  = blockIdx.y * 128;     // batch rows
    const int entchunk = blockIdx.x * CHUNK;   // entry base
    const int gz = blockIdx.z;

    const uint16_t* Wn; int ldw, KT, zoff; unsigned* cdst;
    if (gz == 0)      { Wn = wshn; ldw = DFULL; KT = 16; zoff = 0;   cdst = cand; }
    else if (gz == 1) { Wn = wtn;  ldw = DHALF; KT = 8;  zoff = 0;   cdst = cand + CD1; }
    else              { Wn = wgn;  ldw = DHALF; KT = 8;  zoff = 512; cdst = cand + 2 * CD1; }
    const int ldz = DFULL;

    // ---- hoisted per-thread staging offsets (bytes) ----
    // slot i covers LDS bytes [(i*8+wv)*1024 + lane*16 .. +16), i in {0,1}
    int sw_o0, sw_o1, sz_o0, sz_o1;        // source offsets within panel
    int lw_o0, lw_o1, lz_o0, lz_o1;        // LDS offsets within buffer
    {
        int o, row, kb;
        o = (0 * 8 + wv) * 1024 + lane * 16; row = o >> 7; kb = (o & 127) ^ ((row & 7) << 4);
        sw_o0 = row * (ldw * 2) + kb; lw_o0 = o;
        sz_o0 = row * (ldz * 2) + kb; lz_o0 = o;
        o = (1 * 8 + wv) * 1024 + lane * 16; row = o >> 7; kb = (o & 127) ^ ((row & 7) << 4);
        sw_o1 = row * (ldw * 2) + kb; lw_o1 = o;
        sz_o1 = row * (ldz * 2) + kb; lz_o1 = o;
    }

    const char* Wbase = (const char*)Wn;
    const char* Zbase = (const char*)(Zn + zoff);

    // per-lane sorted lists (descending), packed (sortable16(v)<<16)|entry_idx
    unsigned La0 = 0, La1 = 0, La2 = 0, La3 = 0, La4 = 0;   // batch row n=0
    unsigned Lb0 = 0, Lb1 = 0, Lb2 = 0, Lb3 = 0, Lb4 = 0;   // batch row n=1

    // named staging registers (4 x uint4 = 16 VGPR, never in memory)
    uint4 sw0, sw1, sz0, sz1;

#define LOADG(cb2, kt2) {                                                           \
        const char* Wg = Wbase + ((size_t)(entchunk + (cb2) * 128) * ldw + (kt2) * 64) * 2; \
        const char* Zg = Zbase + ((size_t)rowbase * ldz + (kt2) * 64) * 2;          \
        sw0 = *(const uint4*)(Wg + sw_o0);                                          \
        sw1 = *(const uint4*)(Wg + sw_o1);                                          \
        sz0 = *(const uint4*)(Zg + sz_o0);                                          \
        sz1 = *(const uint4*)(Zg + sz_o1);                                          \
    }
#define WRITES(bufi) {                                                              \
        char* Wd = (char*)&Wsm[bufi][0];                                            \
        char* Zd = (char*)&Zsm[bufi][0];                                            \
        *(uint4*)(Wd + lw_o0) = sw0;                                                \
        *(uint4*)(Wd + lw_o1) = sw1;                                                \
        *(uint4*)(Zd + lz_o0) = sz0;                                                \
        *(uint4*)(Zd + lz_o1) = sz1;                                                \
    }

    LOADG(0, 0);
    WRITES(0);
    __syncthreads();
    int cur = 0;

    for (int cb = 0; cb < 8; ++cb) {
        f32x4 acc[4][2];
        #pragma unroll
        for (int m = 0; m < 4; ++m)
            #pragma unroll
            for (int n = 0; n < 2; ++n)
                acc[m][n] = (f32x4){0.f, 0.f, 0.f, 0.f};

        for (int kt = 0; kt < KT; ++kt) {
            int last = (kt + 1 == KT);
            int ncb = last ? cb + 1 : cb;
            int nkt = last ? 0 : kt + 1;
            int havenext = (ncb < 8);
            if (havenext) LOADG(ncb, nkt);   // issue loads; latency hides under compute

            const char* Wb = (const char*)&Wsm[cur][0];
            const char* Zb = (const char*)&Zsm[cur][0];
            #pragma unroll
            for (int ks = 0; ks < 2; ++ks) {
                int kb = ks * 64 + q * 16;
                bf16x8 b[2];
                #pragma unroll
                for (int n = 0; n < 2; ++n) {
                    int rb = wc * 32 + n * 16 + c;
                    b[n] = *(const bf16x8*)(Zb + rb * 128 + (kb ^ ((rb & 7) << 4)));
                }
                #pragma unroll
                for (int m = 0; m < 4; ++m) {
                    int ra = wr * 64 + m * 16 + c;
                    bf16x8 a = *(const bf16x8*)(Wb + ra * 128 + (kb ^ ((ra & 7) << 4)));
                    #pragma unroll
                    for (int n = 0; n < 2; ++n)
                        acc[m][n] = __builtin_amdgcn_mfma_f32_16x16x32_bf16(
                                        a, b[n], acc[m][n], 0, 0, 0);
                }
            }

            if (havenext) WRITES(cur ^ 1);   // vmcnt wait lands here, post-compute
            __syncthreads();                 // drains LDS writes only (cheap)
            cur ^= 1;
        }

        // ---- per-lane branchless top-5 screen (no cross-lane ops) ----
        const int entbase = entchunk + cb * 128 + wr * 64 + q * 4;
        #pragma unroll
        for (int n = 0; n < 2; ++n) {
            #pragma unroll
            for (int m = 0; m < 4; ++m) {
                #pragma unroll
                for (int i = 0; i < 4; ++i) {
                    unsigned u  = __float_as_uint(acc[m][n][i]);
                    unsigned mg = (unsigned)((int)u >> 31);
                    unsigned h  = (u >> 16) ^ (mg | 0x8000u);
                    unsigned p  = (h << 16) | (unsigned)(entbase + m * 16 + i);
                    if (n == 0) {
                        bool g0 = p > La0, g1 = p > La1, g2 = p > La2,
                             g3 = p > La3, g4 = p > La4;
                        La4 = g4 ? (g3 ? La3 : p) : La4;
                        La3 = g3 ? (g2 ? La2 : p) : La3;
                        La2 = g2 ? (g1 ? La1 : p) : La2;
                        La1 = g1 ? (g0 ? La0 : p) : La1;
                        La0 = g0 ? p : La0;
                    } else {
                        bool g0 = p > Lb0, g1 = p > Lb1, g2 = p > Lb2,
                             g3 = p > Lb3, g4 = p > Lb4;
                        Lb4 = g4 ? (g3 ? Lb3 : p) : Lb4;
                        Lb3 = g3 ? (g2 ? Lb2 : p) : Lb3;
                        Lb2 = g2 ? (g1 ? Lb1 : p) : Lb2;
                        Lb1 = g1 ? (g0 ? Lb0 : p) : Lb1;
                        Lb0 = g0 ? p : Lb0;
                    }
                }
            }
        }
    }

    // write per-lane lists: cand[row][chunk][wr][q][5]
    {
        int grow = rowbase + wc * 32 + 0 * 16 + c;
        unsigned* dst = cdst + ((size_t)grow * NCHUNK + blockIdx.x) * CPC + wr * 20 + q * 5;
        dst[0] = La0; dst[1] = La1; dst[2] = La2; dst[3] = La3; dst[4] = La4;
        grow = rowbase + wc * 32 + 1 * 16 + c;
        dst = cdst + ((size_t)grow * NCHUNK + blockIdx.x) * CPC + wr * 20 + q * 5;
        dst[0] = Lb0; dst[1] = Lb1; dst[2] = Lb2; dst[3] = Lb3; dst[4] = Lb4;
    }
#undef LOADG
#undef WRITES
}

// ---------------- fused merge: all 3 codebooks in one dispatch ----------------
// grid (BATCH, 3). Rescore + mix from bf16 NORMALIZED books (L3-resident),
// f32 z in LDS, f32 accum, scaled by rnz. UNCHANGED from R13 (absmax 1.53e-2,
// deterministic) — scoring path must stay byte-identical.
__global__ __launch_bounds__(256) void k_merge_all(
    const unsigned* __restrict__ cand,
    const uint16_t* __restrict__ wshn, const uint16_t* __restrict__ wtn,
    const uint16_t* __restrict__ wgn,
    const float* __restrict__ rnzt, const float* __restrict__ rnzg,
    const float* __restrict__ z, float* __restrict__ out,
    unsigned int* __restrict__ bm, float* __restrict__ ls)
{
    const int b = blockIdx.x, g = blockIdx.y, tid = threadIdx.x;
    const int lane = tid & 63, wv = tid >> 6;

    // per-codebook config (wave-uniform)
    const unsigned* cd; const uint16_t* emb;
    int zoff, ld;
    float *outm, *outs1, *outs2;
    float rz0, rz1;
    if (g == 0) {
        cd = cand;           emb = wshn; zoff = 0;   ld = DFULL;
        outm = out; outs1 = out + O1; outs2 = out + O2;
        rz0 = rnzt[b]; rz1 = rnzg[b];
    } else if (g == 1) {
        cd = cand + CD1;     emb = wtn;  zoff = 0;   ld = DHALF;
        outm = out + O3; outs1 = nullptr; outs2 = nullptr;
        rz0 = rnzt[b]; rz1 = 0.f;
    } else {
        cd = cand + 2 * CD1; emb = wgn;  zoff = 512; ld = DHALF;
        outm = out + O4; outs1 = nullptr; outs2 = nullptr;
        rz0 = rnzg[b]; rz1 = 0.f;
    }
    unsigned int* bitmap = bm + g * (NE / 32);
    float* lossacc = ls + g;

    __shared__ float zsh[DFULL];
    __shared__ unsigned scand[MRES];
    __shared__ float ssh[MRES];
    __shared__ float wts[TOPK];
    __shared__ int   ish[TOPK];
    __shared__ float serr[4];

    const float* zrow = z + (size_t)b * DFULL + zoff;
    for (int cc = tid; cc < ld / 4; cc += 256)
        ((float4*)zsh)[cc] = ((const float4*)zrow)[cc];

    // wave 0: top-24 of 640 packed candidates (value-clear extraction)
    if (wv == 0) {
        unsigned creg[10];
        const unsigned* cb_ = cd + (size_t)b * NCAND;
        #pragma unroll
        for (int j = 0; j < 10; ++j) creg[j] = cb_[lane + 64 * j];
        for (int k = 0; k < MRES; ++k) {
            unsigned bv = 0;
            #pragma unroll
            for (int j = 0; j < 10; ++j) bv = (creg[j] > bv) ? creg[j] : bv;
            #pragma unroll
            for (int off = 32; off; off >>= 1) {
                unsigned ov = __shfl_xor(bv, off);
                bv = (ov > bv) ? ov : bv;
            }
            #pragma unroll
            for (int j = 0; j < 10; ++j) if (creg[j] == bv) creg[j] = 0u;
            if (lane == 0) scand[k] = bv;
        }
    }
    __syncthreads();

    // rescore the 24 survivors: bf16 normalized books x f32 z, f32 accum
    for (int cc = wv; cc < MRES; cc += 4) {
        int idx = scand[cc] & 0xFFFFu;
        const uint16_t* er = emb + (size_t)idx * ld;
        uint4 e0 = *(const uint4*)(er + lane * 8);
        float t = rz0 * dot8bf(e0, zsh + lane * 8);
        if (ld == DFULL) {
            uint4 e1 = *(const uint4*)(er + 512 + lane * 8);
            t += rz1 * dot8bf(e1, zsh + 512 + lane * 8);
        }
        #pragma unroll
        for (int off = 32; off; off >>= 1) t += __shfl_xor(t, off);
        if (lane == 0) ssh[cc] = t;
    }
    __syncthreads();

    // wave 0: top-10 of 24 -> softmax weights
    if (wv == 0) {
        float val = (lane < MRES) ? ssh[lane] : -1e30f;
        float vk[TOPK]; int sk[TOPK];
        #pragma unroll
        for (int k = 0; k < TOPK; ++k) {
            float v = val; int who = lane;
            #pragma unroll
            for (int off = 32; off; off >>= 1) {
                float ov = __shfl_xor(v, off);
                int   ow = __shfl_xor(who, off);
                if (ov > v || (ov == v && ow < who)) { v = ov; who = ow; }
            }
            vk[k] = v; sk[k] = who;
            if (lane == who) val = -1e30f;
        }
        if (lane == 0) {
            float vmax = vk[0], e[TOPK], sum = 0.f;
            #pragma unroll
            for (int k = 0; k < TOPK; ++k) { e[k] = expf(2.f * (vk[k] - vmax)); sum += e[k]; }
            #pragma unroll
            for (int k = 0; k < TOPK; ++k) {
                float w = e[k] / sum;
                int idx = scand[sk[k]] & 0xFFFFu;
                ish[k] = idx;
                wts[k] = w;
                atomicOr(&bitmap[idx >> 5], 1u << (idx & 31));
            }
        }
    }
    __syncthreads();

    float wk[TOPK]; int ik[TOPK];
    #pragma unroll
    for (int k = 0; k < TOPK; ++k) { wk[k] = wts[k]; ik[k] = ish[k]; }

    // mix from bf16 NORMALIZED codebook rows (8B gathers), write outputs, loss
    float err = 0.f;
    const int ng = ld / 4;
    for (int g2 = tid; g2 < ng; g2 += 256) {
        float ax = 0.f, ay = 0.f, az = 0.f, aw = 0.f;
        #pragma unroll
        for (int k = 0; k < TOPK; ++k) {
            ushort4 e = ((const ushort4*)(emb + (size_t)ik[k] * ld))[g2];
            float wv_ = wk[k];
            ax += wv_ * bf2f(e.x); ay += wv_ * bf2f(e.y);
            az += wv_ * bf2f(e.z); aw += wv_ * bf2f(e.w);
        }
        float4 zz = ((const float4*)zsh)[g2];
        float dx = ax - zz.x, dy = ay - zz.y, dz_ = az - zz.z, dw = aw - zz.w;
        err += dx*dx + dy*dy + dz_*dz_ + dw*dw;
        float4 a4 = {ax, ay, az, aw};
        ((float4*)(outm + (size_t)b * ld))[g2] = a4;
        if (outs1) {
            if (g2 < 128) ((float4*)(outs1 + (size_t)b * DHALF))[g2] = a4;
            else          ((float4*)(outs2 + (size_t)b * DHALF))[g2 - 128] = a4;
        }
    }
    #pragma unroll
    for (int off = 32; off; off >>= 1) err += __shfl_xor(err, off);
    if (lane == 0) serr[wv] = err;
    __syncthreads();
    if (tid == 0) atomicAdd(lossacc, serr[0] + serr[1] + serr[2] + serr[3]);
}

// ---------------- scalar outputs ----------------
__global__ __launch_bounds__(256) void k_scalars(const unsigned int* __restrict__ bm,
                                                 const float* __restrict__ lossacc,
                                                 float* __restrict__ out)
{
    __shared__ float red[4];
    int tid = threadIdx.x;
    float counts[3];
    for (int g = 0; g < 3; ++g) {
        unsigned c = 0;
        for (int w = tid; w < NE / 32; w += 256) c += __popc(bm[g * (NE / 32) + w]);
        float f = (float)c;
        #pragma unroll
        for (int off = 32; off; off >>= 1) f += __shfl_xor(f, off);
        if ((tid & 63) == 0) red[tid >> 6] = f;
        __syncthreads();
        counts[g] = red[0] + red[1] + red[2] + red[3];
        __syncthreads();
    }
    if (tid == 0) {
        float vq_s = lossacc[0] / (4096.f * 1024.f);
        float vq_t = lossacc[1] / (4096.f * 512.f);
        float vq_g = lossacc[2] / (4096.f * 512.f);
        out[0] = vq_s; out[1] = BETA_C * vq_s;
        out[2] = vq_t; out[3] = BETA_C * vq_t;
        out[4] = vq_g; out[5] = BETA_C * vq_g;
        out[6] = counts[0] / (float)NE;
        out[7] = counts[1] / (float)NE;
        out[8] = counts[2] / (float)NE;
    }
}

// ---------------- host launch ----------------
extern "C" void kernel_launch(void* const* d_in, const int* in_sizes, int n_in,
                              void* d_out, int out_size, void* d_ws, size_t ws_size,
                              hipStream_t stream) {
    const float* z    = (const float*)d_in[0];
    const float* w_t  = (const float*)d_in[1];
    const float* w_g  = (const float*)d_in[2];
    const float* w_st = (const float*)d_in[3];
    const float* w_sg = (const float*)d_in[4];
    float* out = (float*)d_out;

    uint8_t* ws = (uint8_t*)d_ws;
    const size_t OFF_ZN  = 0;                                          // bf16 [4096,1024]
    const size_t OFF_WSH = OFF_ZN  + (size_t)BATCH * DFULL * 2;        // bf16 [16384,1024]
    const size_t OFF_WT  = OFF_WSH + (size_t)NE * DFULL * 2;           // bf16 [16384,512]
    const size_t OFF_WG  = OFF_WT  + (size_t)NE * DHALF * 2;
    const size_t OFF_CD  = OFF_WG  + (size_t)NE * DHALF * 2;           // 3*4096*640 u32
    const size_t OFF_RN  = OFF_CD  + (size_t)3 * BATCH * NCAND * 4;
    const size_t OFF_RNZ = OFF_RN  + (size_t)4 * NE * 4;
    const size_t OFF_BM  = OFF_RNZ + (size_t)2 * BATCH * 4;
    const size_t OFF_LS  = OFF_BM  + (size_t)3 * (NE / 8);

    uint16_t* zn   = (uint16_t*)(ws + OFF_ZN);
    uint16_t* wsh  = (uint16_t*)(ws + OFF_WSH);
    uint16_t* wt   = (uint16_t*)(ws + OFF_WT);
    uint16_t* wg   = (uint16_t*)(ws + OFF_WG);
    unsigned* cd   = (unsigned*)(ws + OFF_CD);
    float*    rns  = (float*)(ws + OFF_RN);
    float*    rnzt = (float*)(ws + OFF_RNZ);
    float*    rnzg = rnzt + BATCH;
    unsigned* bm   = (unsigned*)(ws + OFF_BM);
    float*    ls   = (float*)(ws + OFF_LS);

    hipMemsetAsync(ws + OFF_BM, 0, 3 * (NE / 8) + 64, stream);

    k_norm_z<<<BATCH, 256, 0, stream>>>(z, zn, rnzt, rnzg);
    k_norm_cb_all<<<dim3(NE, 4), 128, 0, stream>>>(w_st, w_sg, w_t, w_g,
                                                   wsh, wt, wg, rns);

    k_gemm_topk<<<dim3(NCHUNK, BATCH / 128, 3), 512, 0, stream>>>(zn, wsh, wt, wg, cd);

    k_merge_all<<<dim3(BATCH, 3), 256, 0, stream>>>(
        cd, wsh, wt, wg, rnzt, rnzg, z, out, bm, ls);

    k_scalars<<<1, 256, 0, stream>>>(bm, ls, out + O5);
}